// Round 4
// baseline (2427.956 us; speedup 1.0000x reference)
//
#include <hip/hip_runtime.h>
#include <hip/hip_bf16.h>

using bf16 = __hip_bfloat16;
typedef __bf16 bf16x8v __attribute__((ext_vector_type(8)));
typedef __bf16 bf16x4v __attribute__((ext_vector_type(4)));
typedef float f32x4v __attribute__((ext_vector_type(4)));

#define EMBED 1024
#define FF_DIM 4096
#define NTOK 4096          // BATCH * SEQ
#define SEQL 2048
#define HD 64
#define WBAND 46           // ceil(sqrt(2048))
#define LN_EPS 1e-5f

// ---------------------------------------------------------------------------
// Input-dtype detection (robust): fp32 tensors have random mantissa bits in
// the low halfword (sane-bf16-exponent rate ~20%); bf16 tensors have a real
// N(0,1) bf16 there (rate ~100%). flag: 1 = bf16 inputs, 0 = fp32 inputs.
// Round-3 evidence: fp32 path removed NaN -> expect flag==0 world.
// ---------------------------------------------------------------------------
__global__ __launch_bounds__(256) void detect_dtype(
    const unsigned int* __restrict__ xw, int* __restrict__ flag)
{
  __shared__ int votes[256];
  int v = 0;
#pragma unroll
  for (int j = 0; j < 4; j++) {
    unsigned int w = xw[1 + threadIdx.x * 4 + j];
    unsigned int e = (w >> 7) & 0xFFu;          // low halfword's bf16 exponent
    v += (e == 0u || (e >= 0x58u && e <= 0x88u)) ? 1 : 0;
  }
  votes[threadIdx.x] = v;
  __syncthreads();
  if (threadIdx.x == 0) {
    int s = 0;
    for (int i = 0; i < 256; i++) s += votes[i];
    *flag = (s > 512) ? 1 : 0;
  }
}

// generic param cast -> bf16 internal copy (biases / LN gains), flag-branched
__global__ __launch_bounds__(256) void cast_param(
    const void* __restrict__ src, bf16* __restrict__ dst, int n,
    const int* __restrict__ dflag)
{
  const int is_bf16 = *dflag;
  for (int i = blockIdx.x * 256 + threadIdx.x; i < n; i += gridDim.x * 256)
    dst[i] = is_bf16 ? ((const bf16*)src)[i] : (bf16)(((const float*)src)[i]);
}

// x -> fp32 residual stream + bf16 activation copy, flag-branched
__global__ __launch_bounds__(256) void cast_in(
    const void* __restrict__ x, float* __restrict__ xf,
    bf16* __restrict__ xb, int n, const int* __restrict__ dflag)
{
  const int is_bf16 = *dflag;
  const int i = blockIdx.x * 256 + threadIdx.x;
  if (i < n) {
    float v = is_bf16 ? (float)((const bf16*)x)[i] : ((const float*)x)[i];
    xf[i] = v;
    xb[i] = (bf16)v;
  }
}

// ---------------------------------------------------------------------------
// NT GEMM: C[M,N] = A[M,K] @ W[N,K]^T + bias[N].
// A: bf16 internal. W: raw d_in weights (fp32 or bf16 per flag; converted to
// bf16 during staging). f32 accumulate. 128x128 tile, BK=32, 256 thr
// (4 waves x 4x4 MFMA 16x16x32 bf16). Verified layouts (m89/m91):
//  A-frag m=lane&15,k=(lane>>4)*8+j; B-frag n=lane&15,k=(lane>>4)*8+j;
//  C/D col(n)=lane&15, row(m)=(lane>>4)*4+reg.
// EPI: 0 = bf16 out + bias, 1 = bf16 out + bias + relu
// ---------------------------------------------------------------------------
template<int EPI>
__global__ __launch_bounds__(256) void gemm_nt(
    const bf16* __restrict__ A, const void* __restrict__ Wv, size_t woff,
    const bf16* __restrict__ bias, bf16* __restrict__ C,
    int M, int N, int K, const int* __restrict__ dflag)
{
  __shared__ __align__(16) bf16 lA[128 * 32];
  __shared__ __align__(16) bf16 lB[128 * 32];

  const int is_bf16 = *dflag;
  const int tid  = threadIdx.x;
  const int wave = tid >> 6;
  const int lane = tid & 63;
  const int row0 = blockIdx.x * 128;
  const int col0 = blockIdx.y * 128;
  const int wr0  = (wave >> 1) * 64;
  const int wc0  = (wave & 1) * 64;

  f32x4v acc[4][4];
#pragma unroll
  for (int i = 0; i < 4; i++)
#pragma unroll
    for (int j = 0; j < 4; j++) acc[i][j] = (f32x4v){0.f, 0.f, 0.f, 0.f};

  // staging map: lane -> row = wave*16 + lane/4, kchunk = (lane&3)*8 (8 elems);
  // second pass rows +64. LDS idx = row*32 + kchunk = wave*512 + lane*8.
  const int srow = wave * 16 + (lane >> 2);
  const int skc  = (lane & 3) * 8;
  const bf16*  Ag   = A + (size_t)(row0 + srow) * K + skc;
  const size_t bidx = woff + (size_t)(col0 + srow) * K + skc;   // element index
  bf16* lAp = lA + wave * 512 + lane * 8;
  bf16* lBp = lB + wave * 512 + lane * 8;

  const int fr = lane & 15;
  const int q8 = (lane >> 4) * 8;

  for (int k0 = 0; k0 < K; k0 += 32) {
    bf16x8v va0 = *reinterpret_cast<const bf16x8v*>(Ag + k0);
    bf16x8v va1 = *reinterpret_cast<const bf16x8v*>(Ag + (size_t)64 * K + k0);
    bf16x8v vb0, vb1;
    if (is_bf16) {
      const bf16* Wb = (const bf16*)Wv + bidx + k0;
      vb0 = *reinterpret_cast<const bf16x8v*>(Wb);
      vb1 = *reinterpret_cast<const bf16x8v*>(Wb + (size_t)64 * K);
    } else {
      const float* Wf = (const float*)Wv + bidx + k0;
      f32x4v a0 = *reinterpret_cast<const f32x4v*>(Wf);
      f32x4v a1 = *reinterpret_cast<const f32x4v*>(Wf + 4);
      f32x4v b0 = *reinterpret_cast<const f32x4v*>(Wf + (size_t)64 * K);
      f32x4v b1 = *reinterpret_cast<const f32x4v*>(Wf + (size_t)64 * K + 4);
#pragma unroll
      for (int j = 0; j < 4; j++) {
        vb0[j]     = (__bf16)a0[j];
        vb0[j + 4] = (__bf16)a1[j];
        vb1[j]     = (__bf16)b0[j];
        vb1[j + 4] = (__bf16)b1[j];
      }
    }
    __syncthreads();                         // WAR: previous iter's readers done
    *reinterpret_cast<bf16x8v*>(lAp)        = va0;
    *reinterpret_cast<bf16x8v*>(lAp + 2048) = va1;
    *reinterpret_cast<bf16x8v*>(lBp)        = vb0;
    *reinterpret_cast<bf16x8v*>(lBp + 2048) = vb1;
    __syncthreads();                         // staging visible

    bf16x8v af[4], bfv[4];
#pragma unroll
    for (int i = 0; i < 4; i++)
      af[i] = *reinterpret_cast<const bf16x8v*>(&lA[(wr0 + i * 16 + fr) * 32 + q8]);
#pragma unroll
    for (int j = 0; j < 4; j++)
      bfv[j] = *reinterpret_cast<const bf16x8v*>(&lB[(wc0 + j * 16 + fr) * 32 + q8]);
#pragma unroll
    for (int i = 0; i < 4; i++)
#pragma unroll
      for (int j = 0; j < 4; j++)
        acc[i][j] = __builtin_amdgcn_mfma_f32_16x16x32_bf16(af[i], bfv[j], acc[i][j], 0, 0, 0);
  }

  const int quad = (lane >> 4) * 4;
#pragma unroll
  for (int j = 0; j < 4; j++) {
    const int col = col0 + wc0 + j * 16 + fr;
    const float bv = (float)bias[col];
#pragma unroll
    for (int i = 0; i < 4; i++) {
      const int r0 = row0 + wr0 + i * 16 + quad;
#pragma unroll
      for (int r = 0; r < 4; r++) {
        float v = acc[i][j][r] + bv;
        if (EPI == 1) v = fmaxf(v, 0.f);
        C[(size_t)(r0 + r) * N + col] = (bf16)v;
      }
    }
  }
}

// ---------------------------------------------------------------------------
// Band-sparse attention. One block = 32 query rows of one (b,h); band span
// <= 124. O may alias Q: block's Q reads are staged to LDS before any O
// write, and blocks touch disjoint (rows x head-cols) regions.
// ---------------------------------------------------------------------------
__global__ __launch_bounds__(256) void attn_band(
    const bf16* __restrict__ Q, const bf16* __restrict__ Kp,
    const bf16* __restrict__ Vp, bf16* __restrict__ O)
{
  const int sblk = blockIdx.x;
  const int bh   = blockIdx.y;
  const int b    = bh >> 4;
  const int h    = bh & 15;
  const int s0   = sblk * 32;
  int tlo = s0 - WBAND;       if (tlo < 0) tlo = 0;
  int thi = s0 + 31 + WBAND;  if (thi > SEQL - 1) thi = SEQL - 1;
  const int L = thi - tlo + 1;           // 78..124

  __shared__ __align__(16) bf16  sQ[32][64];
  __shared__ __align__(16) bf16  sK[128][64];
  __shared__ __align__(16) bf16  sV[128][64];
  __shared__ __align__(16) float sS[32][128];
  __shared__ float red[32][8];

  const int tid = threadIdx.x;
  const size_t base = ((size_t)b * SEQL) * EMBED + (size_t)h * HD;

  for (int i = tid; i < 32 * 64; i += 256) {
    int sl = i >> 6, d = i & 63;
    sQ[sl][d] = Q[base + (size_t)(s0 + sl) * EMBED + d];
  }
  for (int i = tid; i < L * 64; i += 256) {
    int tl = i >> 6, d = i & 63;
    size_t ga = base + (size_t)(tlo + tl) * EMBED + d;
    sK[tl][d] = Kp[ga];
    sV[tl][d] = Vp[ga];
  }
  __syncthreads();

  const int sl   = tid & 31;
  const int part = tid >> 5;
  const int s    = s0 + sl;

  float pmax = -1e30f;
  for (int tl = part; tl < L; tl += 8) {
    const int t = tlo + tl;
    int dd = s - t; if (dd < 0) dd = -dd;
    float sc = -1e30f;
    if (dd <= WBAND) {
      float dot = 0.f;
#pragma unroll
      for (int d8 = 0; d8 < 8; d8++) {
        bf16x8v qv = *reinterpret_cast<const bf16x8v*>(&sQ[sl][d8 * 8]);
        bf16x8v kv = *reinterpret_cast<const bf16x8v*>(&sK[tl][d8 * 8]);
#pragma unroll
        for (int j = 0; j < 8; j++) dot += (float)qv[j] * (float)kv[j];
      }
      sc = dot * 0.125f;
    }
    sS[sl][tl] = sc;
    pmax = fmaxf(pmax, sc);
  }
  red[sl][part] = pmax;
  __syncthreads();
  float rmax = -1e30f;
#pragma unroll
  for (int p = 0; p < 8; p++) rmax = fmaxf(rmax, red[sl][p]);
  __syncthreads();

  float psum = 0.f;
  for (int tl = part; tl < L; tl += 8) {
    float e = __expf(sS[sl][tl] - rmax);
    sS[sl][tl] = e;
    psum += e;
  }
  red[sl][part] = psum;
  __syncthreads();
  float rsum = 0.f;
#pragma unroll
  for (int p = 0; p < 8; p++) rsum += red[sl][p];
  const float inv = 1.f / rsum;

  const int dbase = part * 8;
  float o[8] = {0.f, 0.f, 0.f, 0.f, 0.f, 0.f, 0.f, 0.f};
  for (int tl = 0; tl < L; tl++) {
    float p = sS[sl][tl];
    bf16x8v vvv = *reinterpret_cast<const bf16x8v*>(&sV[tl][dbase]);
#pragma unroll
    for (int j = 0; j < 8; j++) o[j] += p * (float)vvv[j];
  }
  const size_t ob = base + (size_t)s * EMBED + dbase;
#pragma unroll
  for (int j = 0; j < 8; j++) O[ob + j] = (bf16)(o[j] * inv);
}

// ---------------------------------------------------------------------------
// Fused residual add + LayerNorm. fp32 residual in/out (xin may == xf_out),
// bf16 GEMM-branch input y, bf16 activation out. Optional final output:
// dtype keyed off dflag (fp32 world -> float*, bf16 world -> bf16*).
// ---------------------------------------------------------------------------
__global__ __launch_bounds__(256) void resid_ln(
    const float* xin, const bf16* __restrict__ y,
    const bf16* __restrict__ g, const bf16* __restrict__ be,
    float* xf_out, bf16* __restrict__ xb_out,
    void* __restrict__ final_out, const int* __restrict__ dflag)
{
  __shared__ float red1[4];
  __shared__ float red2[4];
  const int row = blockIdx.x;
  const int tid = threadIdx.x;
  const size_t base = (size_t)row * EMBED + (size_t)tid * 4;

  f32x4v  xv = *reinterpret_cast<const f32x4v*>(xin + base);
  bf16x4v yv = *reinterpret_cast<const bf16x4v*>(y + base);
  float v[4];
#pragma unroll
  for (int j = 0; j < 4; j++) v[j] = xv[j] + (float)yv[j];

  float s = v[0] + v[1] + v[2] + v[3];
#pragma unroll
  for (int off = 32; off > 0; off >>= 1) s += __shfl_down(s, off, 64);
  if ((tid & 63) == 0) red1[tid >> 6] = s;
  __syncthreads();
  const float mu = (red1[0] + red1[1] + red1[2] + red1[3]) * (1.f / EMBED);

  float sq = 0.f;
#pragma unroll
  for (int j = 0; j < 4; j++) { const float d = v[j] - mu; sq += d * d; }
#pragma unroll
  for (int off = 32; off > 0; off >>= 1) sq += __shfl_down(sq, off, 64);
  if ((tid & 63) == 0) red2[tid >> 6] = sq;
  __syncthreads();
  const float rstd = rsqrtf((red2[0] + red2[1] + red2[2] + red2[3]) * (1.f / EMBED) + LN_EPS);

  bf16x4v gv = *reinterpret_cast<const bf16x4v*>(g + (size_t)tid * 4);
  bf16x4v bv = *reinterpret_cast<const bf16x4v*>(be + (size_t)tid * 4);
  f32x4v of;
  bf16x4v ov;
#pragma unroll
  for (int j = 0; j < 4; j++) {
    of[j] = (v[j] - mu) * rstd * (float)gv[j] + (float)bv[j];
    ov[j] = (__bf16)of[j];
  }
  *reinterpret_cast<f32x4v*>(xf_out + base) = of;
  *reinterpret_cast<bf16x4v*>(xb_out + base) = ov;
  if (final_out) {
    if (*dflag)
      *reinterpret_cast<bf16x4v*>((bf16*)final_out + base) = ov;
    else
      *reinterpret_cast<f32x4v*>((float*)final_out + base) = of;
  }
}

// ---------------------------------------------------------------------------
// ws layout (65 MB peak, liveness-verified):
//  [0,4K) flag | [4K,~112K) bf16 param copies
//  [ 1,17) xf fp32 residual | [17,25) xb bf16 activation
//  [25,33) q (=ao alias)    | [33,41) kk | [41,49) vv
//  [25,57) hh 32MB (aliases q/kk/vv + free [49,57); all dead at FF1)
//  [57,65) y bf16 GEMM out  (disjoint from hh: FF2 reads hh, writes y)
// ---------------------------------------------------------------------------
extern "C" void kernel_launch(void* const* d_in, const int* in_sizes, int n_in,
                              void* d_out, int out_size, void* d_ws, size_t ws_size,
                              hipStream_t stream)
{
  char* ws = (char*)d_ws;
  const size_t MB = 1024 * 1024;
  int*   flag = (int*)ws;
  bf16*  pp   = (bf16*)(ws + 4096);
  float* xf   = (float*)(ws + 1 * MB);
  bf16*  xb   = (bf16*)(ws + 17 * MB);
  bf16*  q    = (bf16*)(ws + 25 * MB);
  bf16*  kk   = (bf16*)(ws + 33 * MB);
  bf16*  vv   = (bf16*)(ws + 41 * MB);
  bf16*  ao   = q;
  bf16*  hh   = (bf16*)(ws + 25 * MB);     // 32 MB
  bf16*  y    = (bf16*)(ws + 57 * MB);

  // bf16 param-copy element offsets within pp
  bf16* pbq = pp;            bf16* pbk = pp + 4096;  bf16* pbv = pp + 8192;
  bf16* pbo = pp + 12288;    bf16* pb1 = pp + 16384; bf16* pb2 = pp + 32768;
  bf16* pg1 = pp + 36864;    bf16* pe1 = pp + 40960;
  bf16* pg2 = pp + 45056;    bf16* pe2 = pp + 49152;

  detect_dtype<<<1, 256, 0, stream>>>((const unsigned int*)d_in[0], flag);

  cast_param<<<16, 256, 0, stream>>>(d_in[2],  pbq, 4096,  flag);
  cast_param<<<16, 256, 0, stream>>>(d_in[4],  pbk, 4096,  flag);
  cast_param<<<16, 256, 0, stream>>>(d_in[6],  pbv, 4096,  flag);
  cast_param<<<16, 256, 0, stream>>>(d_in[8],  pbo, 4096,  flag);
  cast_param<<<64, 256, 0, stream>>>(d_in[10], pb1, 16384, flag);
  cast_param<<<16, 256, 0, stream>>>(d_in[12], pb2, 4096,  flag);
  cast_param<<<16, 256, 0, stream>>>(d_in[13], pg1, 4096,  flag);
  cast_param<<<16, 256, 0, stream>>>(d_in[14], pe1, 4096,  flag);
  cast_param<<<16, 256, 0, stream>>>(d_in[15], pg2, 4096,  flag);
  cast_param<<<16, 256, 0, stream>>>(d_in[16], pe2, 4096,  flag);

  cast_in<<<dim3((NTOK * EMBED) / 256), 256, 0, stream>>>(
      d_in[0], xf, xb, NTOK * EMBED, flag);

  for (int l = 0; l < 4; l++) {
    const size_t wEE = (size_t)l * EMBED * EMBED;
    const size_t wFE = (size_t)l * FF_DIM * EMBED;

    gemm_nt<0><<<dim3(32, 8),  256, 0, stream>>>(xb, d_in[1], wEE, pbq + l * 1024, q,  NTOK, EMBED, EMBED, flag);
    gemm_nt<0><<<dim3(32, 8),  256, 0, stream>>>(xb, d_in[3], wEE, pbk + l * 1024, kk, NTOK, EMBED, EMBED, flag);
    gemm_nt<0><<<dim3(32, 8),  256, 0, stream>>>(xb, d_in[5], wEE, pbv + l * 1024, vv, NTOK, EMBED, EMBED, flag);
    attn_band<<<dim3(SEQL / 32, 32), 256, 0, stream>>>(q, kk, vv, ao);
    gemm_nt<0><<<dim3(32, 8),  256, 0, stream>>>(ao, d_in[7], wEE, pbo + l * 1024, y, NTOK, EMBED, EMBED, flag);
    resid_ln<<<dim3(NTOK), 256, 0, stream>>>(xf, y, pg1 + l * 1024, pe1 + l * 1024, xf, xb, nullptr, flag);
    gemm_nt<1><<<dim3(32, 32), 256, 0, stream>>>(xb, d_in[9], wFE, pb1 + l * 4096, hh, NTOK, FF_DIM, EMBED, flag);
    gemm_nt<0><<<dim3(32, 8),  256, 0, stream>>>(hh, d_in[11], wFE, pb2 + l * 1024, y, NTOK, EMBED, FF_DIM, flag);
    resid_ln<<<dim3(NTOK), 256, 0, stream>>>(xf, y, pg2 + l * 1024, pe2 + l * 1024, xf, xb,
                                             l == 3 ? d_out : nullptr, flag);
  }
}